// Round 11
// baseline (2052.098 us; speedup 1.0000x reference)
//
#include <hip/hip_runtime.h>

// ---------------------------------------------------------------------------
// 2-layer LSTM LM, S=512 B=512 H=256 V=128 — Round 11: stamp-in-data sync.
// 256 blocks = 32 batch-groups x 8 col-blocks; weights VGPR/AGPR-resident
// fp16 MFMA B-fragments. Skewed schedule per iter t: gather h0_{t-1} and
// h1_{t-2} -> MFMA L0(t)+L1(t-1)+proj(t-2) -> epilogues -> publish.
// Exchange words are u32 = (stamp16 << 16) | fp16(h): the poll IS the
// gather (one MALL RT, per-word granularity), and publish needs no drain,
// no tag, no extra barrier (visibility of the stamped word is the signal).
// Slot safety (2 slots, parity t&1) by data dependence: a writer reaching
// t+2 proves all peers consumed stamp-t words. Zero-init never matches
// (stamps start at 1); tail publishes a stamped dummy h0 at t=S.
// 2 barriers/iter. c fp32 in regs; weights fp16 (the 2^-9 error floor).
// ---------------------------------------------------------------------------

#define S_ 512
#define B_ 512
#define H_ 256
#define V_ 128

typedef _Float16 f16;
typedef __attribute__((ext_vector_type(8))) _Float16 f16x8;
typedef __attribute__((ext_vector_type(4))) float f32x4;
typedef unsigned long long u64;
typedef unsigned u32;
typedef unsigned short u16;

// ws BYTE offsets
#define OFF_B0   0          // f16 frags [j8][w8][kk8][64][8]  = 512 KB (w_hh0)
#define OFF_B1   524288     // f16 frags [j8][w8][kk16][64][8] = 1 MB  (w_ih1|w_hh1)
#define OFF_BP   1572864    // f16 frags [j8][w8][64][8]       = 64 KB (W_out)
#define OFF_EX   1638400    // [bg32][slot2][layer2][16][256] u32 = 2 MB

__device__ __forceinline__ float sigm(float z) { return 1.0f / (1.0f + __expf(-z)); }
__device__ __forceinline__ float tanh_fast(float z) {
  return 2.0f / (1.0f + __expf(-2.0f * z)) - 1.0f;
}

// ---------------------------------------------------------------------------
// prep: pack weights into per-(colblock,wave) fp16 MFMA B-fragment streams;
// zero the exchange (stamp 0 never matches). B frag (16x16x32): lane l elem
// i -> B[k][n], k = kk*32+(l>>4)*8+i, n = l&15. Wave w of col-block j:
// gate=w>>1, half=w&1, hcol = j*32 + half*16 + n.
// ---------------------------------------------------------------------------
__global__ void prep_kernel(const float* __restrict__ w_hh0,
                            const float* __restrict__ w_ih1, const float* __restrict__ w_hh1,
                            const float* __restrict__ W_out, void* __restrict__ ws) {
  int idx = blockIdx.x * blockDim.x + threadIdx.x;
  f16* wsh = (f16*)ws;
  if (idx < 32768) {                                  // B0 (w_hh0)
    int j = idx >> 12, w = (idx >> 9) & 7, kk = (idx >> 6) & 7, lane = idx & 63;
    int gate = w >> 1, half = w & 1;
    int hcol = j * 32 + half * 16 + (lane & 15);
    int G = gate * H_ + hcol;
    int k0 = kk * 32 + (lane >> 4) * 8;
    f16x8 v;
    #pragma unroll
    for (int i = 0; i < 8; ++i) v[i] = (f16)w_hh0[G * H_ + k0 + i];
    *(f16x8*)(wsh + idx * 8) = v;
  } else if (idx < 32768 + 65536) {                   // B1 (K=512: w_ih1 | w_hh1)
    int t = idx - 32768;
    int j = t >> 13, w = (t >> 10) & 7, kk = (t >> 6) & 15, lane = t & 63;
    int gate = w >> 1, half = w & 1;
    int hcol = j * 32 + half * 16 + (lane & 15);
    int G = gate * H_ + hcol;
    int k0 = kk * 32 + (lane >> 4) * 8;
    const float* src = (k0 < H_) ? (w_ih1 + G * H_ + k0) : (w_hh1 + G * H_ + (k0 - H_));
    f16x8 v;
    #pragma unroll
    for (int i = 0; i < 8; ++i) v[i] = (f16)src[i];
    *(f16x8*)(wsh + 262144 + t * 8) = v;
  } else if (idx < 32768 + 65536 + 4096) {            // BP (W_out), kk = w
    int t = idx - (32768 + 65536);
    int j = t >> 9, w = (t >> 6) & 7, lane = t & 63;
    int vcol = j * 16 + (lane & 15);
    int k0 = w * 32 + (lane >> 4) * 8;
    f16x8 v;
    #pragma unroll
    for (int i = 0; i < 8; ++i) v[i] = (f16)W_out[vcol * H_ + k0 + i];
    *(f16x8*)(wsh + 786432 + t * 8) = v;
  } else if (idx < 102400 + 262144) {                 // zero exchange (2 MB)
    ((u64*)((char*)ws + OFF_EX))[idx - 102400] = 0ull;
  }
}

__device__ __forceinline__ u64 aload64(const u64* p) {
  return __hip_atomic_load((u64*)p, __ATOMIC_RELAXED, __HIP_MEMORY_SCOPE_AGENT);
}
__device__ __forceinline__ void astore32(u32* p, u32 v) {
  __hip_atomic_store(p, v, __ATOMIC_RELAXED, __HIP_MEMORY_SCOPE_AGENT);
}

// pack low16 halves of a u64's two u32 words into one u32 (fp16 pair)
__device__ __forceinline__ u32 pack2(u64 q) {
  return (u32)(q & 0xffffu) | (((u32)(q >> 32)) << 16);
}

// A-frag read, fragment-layout LDS: conflict-free (lane-consecutive 16B)
__device__ __forceinline__ f16x8 afrag(const f16* buf, int lane, int kk) {
  return *(const f16x8*)(buf + kk * 512 + lane * 8);
}

__global__ __launch_bounds__(512, 2) void lstm_r11(const int* __restrict__ x,
                                                   const f16* __restrict__ wts,
                                                   u32* __restrict__ ex,
                                                   const float* __restrict__ w_ih0,
                                                   const float* __restrict__ b_ih0,
                                                   const float* __restrict__ b_hh0,
                                                   const float* __restrict__ b_ih1,
                                                   const float* __restrict__ b_hh1,
                                                   const float* __restrict__ b_out,
                                                   float* __restrict__ out) {
  __shared__ __align__(16) f16 H0[4096], H1[4096];    // 16 KB, frag layout
  __shared__ __align__(16) float gsc0[4][16][33];
  __shared__ __align__(16) float gsc1[4][16][33];
  __shared__ __align__(16) float ppart[4][8][64];

  const int tid  = threadIdx.x;
  const int lane = tid & 63;
  const int w    = tid >> 6;            // wave 0..7: gate = w>>1, half = w&1
  const int bg   = blockIdx.x >> 3;     // batch group 0..31 (16 rows)
  const int j    = blockIdx.x & 7;      // col block 0..7 (32 h-cols)

  // ---- persistent weight fragments (VGPR/AGPR resident) ----
  f16x8 B0r[8], B1r[16], BPr;
  {
    const f16* p0 = wts + (size_t)(j * 8 + w) * 8 * 512 + lane * 8;
    #pragma unroll
    for (int kk = 0; kk < 8; ++kk) B0r[kk] = *(const f16x8*)(p0 + kk * 512);
    const f16* p1 = wts + 262144 + (size_t)(j * 8 + w) * 16 * 512 + lane * 8;
    #pragma unroll
    for (int kk = 0; kk < 16; ++kk) B1r[kk] = *(const f16x8*)(p1 + kk * 512);
    BPr = *(const f16x8*)(wts + 786432 + (size_t)(j * 8 + w) * 512 + lane * 8);
  }

  // ---- per-thread epilogue constants: (erow = tid>>5, ecol = tid&31) ----
  const int erow = tid >> 5, ecol = tid & 31;
  const int hcol = j * 32 + ecol;
  const int browg = bg * 16 + erow;
  float wxv[4], bz0v[4], bz1v[4];
  #pragma unroll
  for (int g = 0; g < 4; ++g) {
    int G = g * H_ + hcol;
    wxv[g]  = w_ih0[G];
    bz0v[g] = b_ih0[G] + b_hh0[G];
    bz1v[g] = b_ih1[G] + b_hh1[G];
  }
  const float bo = (tid < 256) ? b_out[j * 16 + (tid & 15)] : 0.f;

  u32* exG = ex + (size_t)bg * 16384;                 // [slot2][layer2][16][256]

  // gather indexing: wave w == peer w == frag tile kk=w; 8 u32 per thread/layer
  const int grow = lane & 15;
  const int gcol = w * 32 + ((lane >> 4) << 3);
  const int gidx = grow * 256 + gcol;                 // u32 index in [16][256]

  float c0 = 0.f, c1 = 0.f;

  // zero LDS h buffers (h0_{-1} = h1_{-2} = 0)
  ((u64*)H0)[tid] = 0ull; ((u64*)H0)[tid + 512] = 0ull;
  ((u64*)H1)[tid] = 0ull; ((u64*)H1)[tid + 512] = 0ull;
  __syncthreads();

  #pragma unroll 1
  for (int t = 0; t <= S_ + 1; ++t) {
    // x for this thread's row (issued before poll -> overlaps sync latency)
    float xf = (t < S_) ? (float)x[t * B_ + browg] : 0.f;

    // ---- (1) fused poll+gather: loads ARE the arrival check ----
    if (t > 0) {
      const u32 want = (u32)t & 0xffffu;
      const u64 pat  = ((u64)want << 16) | ((u64)want << 48);
      const u64 mask = 0xffff0000ffff0000ull;
      const u64* p0 = (const u64*)(exG + ((t - 1) & 1) * 8192 + gidx);
      const u64* p1 = p0 + 2048;                      // +4096 u32 = layer 1
      u64 a0, a1, a2, a3, b0, b1, b2, b3;
      for (;;) {
        a0 = aload64(p0);     a1 = aload64(p0 + 1);
        a2 = aload64(p0 + 2); a3 = aload64(p0 + 3);
        b0 = aload64(p1);     b1 = aload64(p1 + 1);
        b2 = aload64(p1 + 2); b3 = aload64(p1 + 3);
        u64 bad = (a0 ^ pat) | (a1 ^ pat) | (a2 ^ pat) | (a3 ^ pat)
                | (b0 ^ pat) | (b1 ^ pat) | (b2 ^ pat) | (b3 ^ pat);
        if ((bad & mask) == 0) break;
        __builtin_amdgcn_s_sleep(1);
      }
      asm volatile("" ::: "memory");
      u32* d0 = (u32*)H0 + tid * 4;
      u32* d1 = (u32*)H1 + tid * 4;
      d0[0] = pack2(a0); d0[1] = pack2(a1); d0[2] = pack2(a2); d0[3] = pack2(a3);
      d1[0] = pack2(b0); d1[1] = pack2(b1); d1[2] = pack2(b2); d1[3] = pack2(b3);
    }
    __syncthreads();                                  // B1

    // ---- (2) MFMA: L0(t), L1(t-1), proj(t-2) — 25 MFMAs ----
    {
      f32x4 acc0 = {0.f, 0.f, 0.f, 0.f};
      f32x4 acc1 = {0.f, 0.f, 0.f, 0.f};
      f32x4 ap   = {0.f, 0.f, 0.f, 0.f};
      #pragma unroll
      for (int kk = 0; kk < 8; ++kk) {
        f16x8 ah = afrag(H0, lane, kk);
        acc0 = __builtin_amdgcn_mfma_f32_16x16x32_f16(ah, B0r[kk], acc0, 0, 0, 0);
        acc1 = __builtin_amdgcn_mfma_f32_16x16x32_f16(ah, B1r[kk], acc1, 0, 0, 0);
      }
      #pragma unroll
      for (int kk = 0; kk < 8; ++kk) {
        f16x8 ah = afrag(H1, lane, kk);
        acc1 = __builtin_amdgcn_mfma_f32_16x16x32_f16(ah, B1r[kk + 8], acc1, 0, 0, 0);
      }
      ap = __builtin_amdgcn_mfma_f32_16x16x32_f16(afrag(H1, lane, w), BPr, ap, 0, 0, 0);
      const int gate = w >> 1, half = w & 1;
      const int c16 = lane & 15, r0 = (lane >> 4) * 4;
      #pragma unroll
      for (int r = 0; r < 4; ++r) {
        gsc0[gate][r0 + r][half * 16 + c16] = acc0[r];
        gsc1[gate][r0 + r][half * 16 + c16] = acc1[r];
        ppart[r][w][lane] = ap[r];
      }
    }
    __syncthreads();                                  // B2

    // ---- (3) epilogues + stamped publishes into slot[t&1] ----
    u32* slotW = exG + (t & 1) * 8192;
    const u32 stamp = ((u32)(t + 1) & 0xffffu) << 16;
    if (t <= S_) {                        // layer0 step t -> h0_t (dummy at t==S_)
      u32 word = stamp;
      if (t < S_) {
        float gi = gsc0[0][erow][ecol] + xf * wxv[0] + bz0v[0];
        float gf = gsc0[1][erow][ecol] + xf * wxv[1] + bz0v[1];
        float gg = gsc0[2][erow][ecol] + xf * wxv[2] + bz0v[2];
        float go = gsc0[3][erow][ecol] + xf * wxv[3] + bz0v[3];
        c0 = sigm(gf) * c0 + sigm(gi) * tanh_fast(gg);
        float h0 = sigm(go) * tanh_fast(c0);
        union { f16 h; u16 u; } hb; hb.h = (f16)h0;
        word |= (u32)hb.u;
      }
      astore32(slotW + erow * 256 + hcol, word);
    }
    if (t <= S_) {                        // layer1 step t-1 -> h1_{t-1}
      float h1 = 0.f;
      if (t >= 1) {
        float gi = gsc1[0][erow][ecol] + bz1v[0];
        float gf = gsc1[1][erow][ecol] + bz1v[1];
        float gg = gsc1[2][erow][ecol] + bz1v[2];
        float go = gsc1[3][erow][ecol] + bz1v[3];
        c1 = sigm(gf) * c1 + sigm(gi) * tanh_fast(gg);
        h1 = sigm(go) * tanh_fast(c1);
      }
      union { f16 h; u16 u; } hb; hb.h = (f16)h1;
      astore32(slotW + 4096 + erow * 256 + hcol, stamp | (u32)hb.u);
    }
    if (t >= 2 && tid < 256) {            // projection step t-2 -> out
      int prow = tid >> 4, pvc = tid & 15;
      int plane = (prow >> 2) * 16 + pvc, preg = prow & 3;
      float s = bo;
      #pragma unroll
      for (int ww = 0; ww < 8; ++ww) s += ppart[preg][ww][plane];
      out[((size_t)((t - 2) * B_ + bg * 16 + prow)) * V_ + j * 16 + pvc] = s;
    }
    // no drain, no tag, no third barrier: stamped words are the signal
  }
}

extern "C" void kernel_launch(void* const* d_in, const int* in_sizes, int n_in,
                              void* d_out, int out_size, void* d_ws, size_t ws_size,
                              hipStream_t stream) {
  const int*   x     = (const int*)d_in[0];
  const float* w_ih0 = (const float*)d_in[1];
  const float* w_hh0 = (const float*)d_in[2];
  const float* b_ih0 = (const float*)d_in[3];
  const float* b_hh0 = (const float*)d_in[4];
  const float* w_ih1 = (const float*)d_in[5];
  const float* w_hh1 = (const float*)d_in[6];
  const float* b_ih1 = (const float*)d_in[7];
  const float* b_hh1 = (const float*)d_in[8];
  const float* W_out = (const float*)d_in[9];
  const float* b_out = (const float*)d_in[10];

  // prep threads: 102400 + 262144 = 364544 = 1424 * 256
  prep_kernel<<<1424, 256, 0, stream>>>(w_hh0, w_ih1, w_hh1, W_out, d_ws);

  lstm_r11<<<256, 512, 0, stream>>>(x, (const f16*)d_ws,
                                    (u32*)((char*)d_ws + OFF_EX),
                                    w_ih0, b_ih0, b_hh0, b_ih1, b_hh1, b_out,
                                    (float*)d_out);
}

// Round 12
// 1805.775 us; speedup vs baseline: 1.1364x; 1.1364x over previous
//
#include <hip/hip_runtime.h>

// ---------------------------------------------------------------------------
// 2-layer LSTM LM, S=512 B=512 H=256 V=128 — Round 12: stamped combined-u64
// exchange, coalesced gather, sentinel pre-poll, own-slice LDS shortcut.
// 256 blocks = 32 batch-groups x 8 col-blocks; weights VGPR/AGPR-resident.
// Skew per iter t: L0(t) + L1(t-1) + proj(t-2). Exchange word (per h-col,
// per batch-row) u64 = (stamp<<48)|(h1_{t-1}<<32)|(stamp<<16)|h0_t, one
// atomic store per thread, NO drain/tag/extra barrier. Readers: wave w owns
// peer w's slice; one-sentinel pre-poll then a single coalesced gather
// (lane l -> row l>>2, 16B piece l&3: every instruction tiles 16 full 64B
// lines) + stamp verify (retry rare). Wave j==own col-block skips exchange:
// epilogue writes h directly into LDS tile j. 2 barriers/iter.
// Slot safety by data dependence (writer at t proves peers consumed t-1).
// h single fp16; c fp32 in regs; fp16 weights (the 2^-9 error floor).
// ---------------------------------------------------------------------------

#define S_ 512
#define B_ 512
#define H_ 256
#define V_ 128

typedef _Float16 f16;
typedef __attribute__((ext_vector_type(8))) _Float16 f16x8;
typedef __attribute__((ext_vector_type(4))) float f32x4;
typedef unsigned long long u64;
typedef unsigned u32;
typedef unsigned short u16;

// ws BYTE offsets
#define OFF_B0   0          // f16 frags [j8][w8][kk8][64][8]  = 512 KB (w_hh0)
#define OFF_B1   524288     // f16 frags [j8][w8][kk16][64][8] = 1 MB  (w_ih1|w_hh1)
#define OFF_BP   1572864    // f16 frags [j8][w8][64][8]       = 64 KB (W_out)
#define OFF_EX   1638400    // [bg32][slot2][16][256] u64 = 2 MB

__device__ __forceinline__ float sigm(float z) { return 1.0f / (1.0f + __expf(-z)); }
__device__ __forceinline__ float tanh_fast(float z) {
  return 2.0f / (1.0f + __expf(-2.0f * z)) - 1.0f;
}

// ---------------------------------------------------------------------------
// prep: pack weights into per-(colblock,wave) fp16 MFMA B-fragment streams;
// zero the exchange (stamp 0 never matches). B frag (16x16x32): lane l elem
// i -> B[k][n], k = kk*32+(l>>4)*8+i, n = l&15. Wave w of col-block j:
// gate=w>>1, half=w&1, hcol = j*32 + half*16 + n.
// ---------------------------------------------------------------------------
__global__ void prep_kernel(const float* __restrict__ w_hh0,
                            const float* __restrict__ w_ih1, const float* __restrict__ w_hh1,
                            const float* __restrict__ W_out, void* __restrict__ ws) {
  int idx = blockIdx.x * blockDim.x + threadIdx.x;
  f16* wsh = (f16*)ws;
  if (idx < 32768) {                                  // B0 (w_hh0)
    int j = idx >> 12, w = (idx >> 9) & 7, kk = (idx >> 6) & 7, lane = idx & 63;
    int gate = w >> 1, half = w & 1;
    int hcol = j * 32 + half * 16 + (lane & 15);
    int G = gate * H_ + hcol;
    int k0 = kk * 32 + (lane >> 4) * 8;
    f16x8 v;
    #pragma unroll
    for (int i = 0; i < 8; ++i) v[i] = (f16)w_hh0[G * H_ + k0 + i];
    *(f16x8*)(wsh + idx * 8) = v;
  } else if (idx < 32768 + 65536) {                   // B1 (K=512: w_ih1 | w_hh1)
    int t = idx - 32768;
    int j = t >> 13, w = (t >> 10) & 7, kk = (t >> 6) & 15, lane = t & 63;
    int gate = w >> 1, half = w & 1;
    int hcol = j * 32 + half * 16 + (lane & 15);
    int G = gate * H_ + hcol;
    int k0 = kk * 32 + (lane >> 4) * 8;
    const float* src = (k0 < H_) ? (w_ih1 + G * H_ + k0) : (w_hh1 + G * H_ + (k0 - H_));
    f16x8 v;
    #pragma unroll
    for (int i = 0; i < 8; ++i) v[i] = (f16)src[i];
    *(f16x8*)(wsh + 262144 + t * 8) = v;
  } else if (idx < 32768 + 65536 + 4096) {            // BP (W_out), kk = w
    int t = idx - (32768 + 65536);
    int j = t >> 9, w = (t >> 6) & 7, lane = t & 63;
    int vcol = j * 16 + (lane & 15);
    int k0 = w * 32 + (lane >> 4) * 8;
    f16x8 v;
    #pragma unroll
    for (int i = 0; i < 8; ++i) v[i] = (f16)W_out[vcol * H_ + k0 + i];
    *(f16x8*)(wsh + 786432 + t * 8) = v;
  } else if (idx < 102400 + 262144) {                 // zero exchange (2 MB)
    ((u64*)((char*)ws + OFF_EX))[idx - 102400] = 0ull;
  }
}

__device__ __forceinline__ u64 aload64(const u64* p) {
  return __hip_atomic_load((u64*)p, __ATOMIC_RELAXED, __HIP_MEMORY_SCOPE_AGENT);
}
__device__ __forceinline__ void astore64(u64* p, u64 v) {
  __hip_atomic_store(p, v, __ATOMIC_RELAXED, __HIP_MEMORY_SCOPE_AGENT);
}

// A-frag read, fragment-layout LDS: conflict-free (lane-consecutive 16B)
__device__ __forceinline__ f16x8 afrag(const f16* buf, int lane, int kk) {
  return *(const f16x8*)(buf + kk * 512 + lane * 8);
}

__global__ __launch_bounds__(512, 2) void lstm_r12(const int* __restrict__ x,
                                                   const f16* __restrict__ wts,
                                                   u64* __restrict__ ex,
                                                   const float* __restrict__ w_ih0,
                                                   const float* __restrict__ b_ih0,
                                                   const float* __restrict__ b_hh0,
                                                   const float* __restrict__ b_ih1,
                                                   const float* __restrict__ b_hh1,
                                                   const float* __restrict__ b_out,
                                                   float* __restrict__ out) {
  __shared__ __align__(16) f16 H0[4096], H1[4096];    // 16 KB, frag layout
  __shared__ __align__(16) float gsc0[4][16][33];
  __shared__ __align__(16) float gsc1[4][16][33];
  __shared__ __align__(16) float ppart[4][8][64];

  const int tid  = threadIdx.x;
  const int lane = tid & 63;
  const int w    = tid >> 6;            // wave 0..7: gate = w>>1, half = w&1
  const int bg   = blockIdx.x >> 3;     // batch group 0..31 (16 rows)
  const int j    = blockIdx.x & 7;      // col block 0..7 (32 h-cols)

  // ---- persistent weight fragments (VGPR/AGPR resident) ----
  f16x8 B0r[8], B1r[16], BPr;
  {
    const f16* p0 = wts + (size_t)(j * 8 + w) * 8 * 512 + lane * 8;
    #pragma unroll
    for (int kk = 0; kk < 8; ++kk) B0r[kk] = *(const f16x8*)(p0 + kk * 512);
    const f16* p1 = wts + 262144 + (size_t)(j * 8 + w) * 16 * 512 + lane * 8;
    #pragma unroll
    for (int kk = 0; kk < 16; ++kk) B1r[kk] = *(const f16x8*)(p1 + kk * 512);
    BPr = *(const f16x8*)(wts + 786432 + (size_t)(j * 8 + w) * 512 + lane * 8);
  }

  // ---- per-thread epilogue constants: (erow = tid>>5, ecol = tid&31) ----
  const int erow = tid >> 5, ecol = tid & 31;
  const int hcol = j * 32 + ecol;
  const int browg = bg * 16 + erow;
  float wxv[4], bz0v[4], bz1v[4];
  #pragma unroll
  for (int g = 0; g < 4; ++g) {
    int G = g * H_ + hcol;
    wxv[g]  = w_ih0[G];
    bz0v[g] = b_ih0[G] + b_hh0[G];
    bz1v[g] = b_ih1[G] + b_hh1[G];
  }
  const float bo = (tid < 256) ? b_out[j * 16 + (tid & 15)] : 0.f;

  u64* exG = ex + (size_t)bg * 8192;    // [slot2][16 rows][256 cols] u64

  // epilogue LDS tile-j position (f16 idx): frag layout for (erow, ecol)
  const int fij = j * 512 + (erow + 16 * (ecol >> 3)) * 8 + (ecol & 7);

  // gather mapping: lane l -> row l>>2, 16B piece l&3 (per instr i: piece 4i+(l&3))
  const int grow2 = lane >> 2;

  float c0 = 0.f, c1 = 0.f;

  // zero LDS h buffers (h0_{-1} = h1_{-2} = 0)
  ((u64*)H0)[tid] = 0ull; ((u64*)H0)[tid + 512] = 0ull;
  ((u64*)H1)[tid] = 0ull; ((u64*)H1)[tid + 512] = 0ull;
  __syncthreads();

  #pragma unroll 1
  for (int t = 0; t <= S_ + 1; ++t) {
    // x for this thread's row (issued before poll -> overlaps sync latency)
    float xf = (t < S_) ? (float)x[t * B_ + browg] : 0.f;

    // ---- (1) sentinel pre-poll + coalesced stamped gather (wave w != j) --
    if (t > 0 && w != j) {
      const u32 st  = (u32)t & 0xffffu;
      const u64 pat = ((u64)st << 48) | ((u64)st << 16);
      const u64 msk = 0xffff0000ffff0000ull;
      const u64* sb = exG + ((t - 1) & 1) * 4096;
      // cheap pre-poll: one word of peer w's slice (row 0, col w*32)
      while (((aload64(sb + w * 32) ^ pat) & msk) != 0)
        __builtin_amdgcn_s_sleep(1);
      asm volatile("" ::: "memory");
      // bulk gather: 4 paired u64 loads; instruction's 64 lanes tile 16 lines
      const u64* base = sb + grow2 * 256 + w * 32 + (lane & 3) * 2;
      u64 q0, q1, q2, q3, q4, q5, q6, q7;
      for (;;) {
        q0 = aload64(base);      q1 = aload64(base + 1);
        q2 = aload64(base + 8);  q3 = aload64(base + 9);
        q4 = aload64(base + 16); q5 = aload64(base + 17);
        q6 = aload64(base + 24); q7 = aload64(base + 25);
        u64 bad = (q0 ^ pat) | (q1 ^ pat) | (q2 ^ pat) | (q3 ^ pat)
                | (q4 ^ pat) | (q5 ^ pat) | (q6 ^ pat) | (q7 ^ pat);
        if (!__any((int)((bad & msk) != 0))) break;
        __builtin_amdgcn_s_sleep(1);
      }
      // LDS stage: u32 index w*256 + i*64 + lane (lane-consecutive)
      u32* d0 = (u32*)H0;
      u32* d1 = (u32*)H1;
      d0[w * 256 +   0 + lane] = (u32)(q0 & 0xffffu) | ((u32)(q1 & 0xffffu) << 16);
      d1[w * 256 +   0 + lane] = (u32)((q0 >> 32) & 0xffffu) | ((u32)((q1 >> 32) & 0xffffu) << 16);
      d0[w * 256 +  64 + lane] = (u32)(q2 & 0xffffu) | ((u32)(q3 & 0xffffu) << 16);
      d1[w * 256 +  64 + lane] = (u32)((q2 >> 32) & 0xffffu) | ((u32)((q3 >> 32) & 0xffffu) << 16);
      d0[w * 256 + 128 + lane] = (u32)(q4 & 0xffffu) | ((u32)(q5 & 0xffffu) << 16);
      d1[w * 256 + 128 + lane] = (u32)((q4 >> 32) & 0xffffu) | ((u32)((q5 >> 32) & 0xffffu) << 16);
      d0[w * 256 + 192 + lane] = (u32)(q6 & 0xffffu) | ((u32)(q7 & 0xffffu) << 16);
      d1[w * 256 + 192 + lane] = (u32)((q6 >> 32) & 0xffffu) | ((u32)((q7 >> 32) & 0xffffu) << 16);
    }
    __syncthreads();                                  // B1

    // ---- (2) MFMA: L0(t), L1(t-1), proj(t-2) — 25 MFMAs ----
    {
      f32x4 acc0 = {0.f, 0.f, 0.f, 0.f};
      f32x4 acc1 = {0.f, 0.f, 0.f, 0.f};
      f32x4 ap   = {0.f, 0.f, 0.f, 0.f};
      #pragma unroll
      for (int kk = 0; kk < 8; ++kk) {
        f16x8 ah = afrag(H0, lane, kk);
        acc0 = __builtin_amdgcn_mfma_f32_16x16x32_f16(ah, B0r[kk], acc0, 0, 0, 0);
        acc1 = __builtin_amdgcn_mfma_f32_16x16x32_f16(ah, B1r[kk], acc1, 0, 0, 0);
      }
      #pragma unroll
      for (int kk = 0; kk < 8; ++kk) {
        f16x8 ah = afrag(H1, lane, kk);
        acc1 = __builtin_amdgcn_mfma_f32_16x16x32_f16(ah, B1r[kk + 8], acc1, 0, 0, 0);
      }
      ap = __builtin_amdgcn_mfma_f32_16x16x32_f16(afrag(H1, lane, w), BPr, ap, 0, 0, 0);
      const int gate = w >> 1, half = w & 1;
      const int c16 = lane & 15, r0 = (lane >> 4) * 4;
      #pragma unroll
      for (int r = 0; r < 4; ++r) {
        gsc0[gate][r0 + r][half * 16 + c16] = acc0[r];
        gsc1[gate][r0 + r][half * 16 + c16] = acc1[r];
        ppart[r][w][lane] = ap[r];
      }
    }
    __syncthreads();                                  // B2

    // ---- (3) epilogues: combined u64 publish + own-tile LDS write ----
    if (t <= S_) {
      float h0f = 0.f;
      if (t < S_) {
        float gi = gsc0[0][erow][ecol] + xf * wxv[0] + bz0v[0];
        float gf = gsc0[1][erow][ecol] + xf * wxv[1] + bz0v[1];
        float gg = gsc0[2][erow][ecol] + xf * wxv[2] + bz0v[2];
        float go = gsc0[3][erow][ecol] + xf * wxv[3] + bz0v[3];
        c0 = sigm(gf) * c0 + sigm(gi) * tanh_fast(gg);
        h0f = sigm(go) * tanh_fast(c0);
      }
      float h1f = 0.f;
      if (t >= 1) {
        float gi = gsc1[0][erow][ecol] + bz1v[0];
        float gf = gsc1[1][erow][ecol] + bz1v[1];
        float gg = gsc1[2][erow][ecol] + bz1v[2];
        float go = gsc1[3][erow][ecol] + bz1v[3];
        c1 = sigm(gf) * c1 + sigm(gi) * tanh_fast(gg);
        h1f = sigm(go) * tanh_fast(c1);
      }
      union { f16 h; u16 u; } ha, hb;
      ha.h = (f16)h0f; hb.h = (f16)h1f;
      // own col-block tile -> LDS directly (wave j never touches exchange)
      H0[fij] = ha.h;
      H1[fij] = hb.h;
      const u32 st1 = (u32)(t + 1) & 0xffffu;
      u64 word = ((u64)st1 << 48) | ((u64)hb.u << 32) | ((u64)st1 << 16) | (u64)ha.u;
      astore64(exG + (t & 1) * 4096 + erow * 256 + hcol, word);
    }
    if (t >= 2 && tid < 256) {            // projection step t-2 -> out
      int prow = tid >> 4, pvc = tid & 15;
      int plane = (prow >> 2) * 16 + pvc, preg = prow & 3;
      float s = bo;
      #pragma unroll
      for (int ww = 0; ww < 8; ++ww) s += ppart[preg][ww][plane];
      out[((size_t)((t - 2) * B_ + bg * 16 + prow)) * V_ + j * 16 + pvc] = s;
    }
    // no drain, no tag, no third barrier: stamped words are the signal
  }
}

extern "C" void kernel_launch(void* const* d_in, const int* in_sizes, int n_in,
                              void* d_out, int out_size, void* d_ws, size_t ws_size,
                              hipStream_t stream) {
  const int*   x     = (const int*)d_in[0];
  const float* w_ih0 = (const float*)d_in[1];
  const float* w_hh0 = (const float*)d_in[2];
  const float* b_ih0 = (const float*)d_in[3];
  const float* b_hh0 = (const float*)d_in[4];
  const float* w_ih1 = (const float*)d_in[5];
  const float* w_hh1 = (const float*)d_in[6];
  const float* b_ih1 = (const float*)d_in[7];
  const float* b_hh1 = (const float*)d_in[8];
  const float* W_out = (const float*)d_in[9];
  const float* b_out = (const float*)d_in[10];

  // prep threads: 102400 + 262144 = 364544 = 1424 * 256
  prep_kernel<<<1424, 256, 0, stream>>>(w_hh0, w_ih1, w_hh1, W_out, d_ws);

  lstm_r12<<<256, 512, 0, stream>>>(x, (const f16*)d_ws,
                                    (u64*)((char*)d_ws + OFF_EX),
                                    w_ih0, b_ih0, b_hh0, b_ih1, b_hh1, b_out,
                                    (float*)d_out);
}